// Round 22
// baseline (459.671 us; speedup 1.0000x reference)
//
#include <hip/hip_runtime.h>

#define BB 64
#define TT 512
#define DD 768
#define LL 5
#define NSEQ 128
#define NTOK 65536
#define NEG_INF (-1e30f)
#define IDENT_W 0x4688u   // bp word encoding j->j (0|1<<3|2<<6|3<<9|4<<12)

typedef float floatx4 __attribute__((ext_vector_type(4)));

// Wave64 sum via DPP on the VALU pipe. Result valid in lane 63.
__device__ __forceinline__ float wave_sum_dpp(float v) {
    int t;
    t = __builtin_amdgcn_update_dpp(0, __float_as_int(v), 0x111, 0xf, 0xf, false);
    v += __int_as_float(t);
    t = __builtin_amdgcn_update_dpp(0, __float_as_int(v), 0x112, 0xf, 0xf, false);
    v += __int_as_float(t);
    t = __builtin_amdgcn_update_dpp(0, __float_as_int(v), 0x114, 0xf, 0xf, false);
    v += __int_as_float(t);
    t = __builtin_amdgcn_update_dpp(0, __float_as_int(v), 0x118, 0xf, 0xf, false);
    v += __int_as_float(t);
    t = __builtin_amdgcn_update_dpp(0, __float_as_int(v), 0x142, 0xa, 0xf, false);
    v += __int_as_float(t);
    t = __builtin_amdgcn_update_dpp(0, __float_as_int(v), 0x143, 0xc, 0xf, false);
    v += __int_as_float(t);
    return v;
}

// ---------------------------------------------------------------------------
// ONE kernel, two roles (no grid barrier):
//  blocks 0..1023  : logits producer. Wave w=bid*8+wv handles 8 consecutive
//                    tokens of seq n; seq completion order 0,64,1,65,... so
//                    viterbi pairs (bb,bb+64) become ready together. After its
//                    tokens, lane63 release-increments seqflag[n].
//  blocks 1024..1215: scan consumer (R16-proven body). Spins (tid0) on
//                    seqflag acquire until its sequence(s) complete. Folded
//                    final via ctr. In-order dispatch => producers placed
//                    first => deadlock-free.
// ---------------------------------------------------------------------------
__global__ __launch_bounds__(512) void k_all(const float* __restrict__ x,
                                             const int* __restrict__ label,
                                             const int* __restrict__ seqlen,
                                             const float* __restrict__ W,
                                             const float* __restrict__ bias,
                                             const float* __restrict__ trans,
                                             float* __restrict__ logits,
                                             float* __restrict__ out,
                                             float* __restrict__ losspart,
                                             int* __restrict__ okpart,
                                             int* __restrict__ ctr,
                                             int* __restrict__ seqflag) {
    __shared__ float s_lg[2][TT * LL + 8];
    __shared__ float s_P[1600];
    __shared__ float s_Q[800];
    __shared__ float s_A[2][33 * 5];
    __shared__ float s_tr[25];
    __shared__ float s_etr[25];
    __shared__ unsigned s_mapw[2][32];
    __shared__ int s_B[2][33];
    __shared__ int s_tags[2][TT];
    __shared__ float s_ws[8];
    __shared__ int s_wok[8];
    __shared__ int s_last;

    const int tid = threadIdx.x;
    const int bid = blockIdx.x;

    if (bid < 1024) {
        // ================= logits producer =================
        const int lane = tid & 63;
        const int w    = bid * 8 + (tid >> 6);      // 0..8191
        const int q    = w >> 6;                    // 0..127 completion slot
        const int n    = ((q & 1) << 6) + (q >> 1); // 0,64,1,65,...
        const int t0   = (w & 63) << 3;
        const int sl   = seqlen[n & (BB - 1)];
        const int nact = min(8, sl - t0);
        if (nact <= 0) return;

        float wreg[3][4][LL];
        {
            const floatx4* W4 = reinterpret_cast<const floatx4*>(W);
#pragma unroll
            for (int p = 0; p < 3; ++p) {
                const int base4 = p * 320 + lane * 5;
#pragma unroll
                for (int j = 0; j < 5; ++j) {
                    const floatx4 v = W4[base4 + j];
                    wreg[p][(j * 4 + 0) / 5][(j * 4 + 0) % 5] = v.x;
                    wreg[p][(j * 4 + 1) / 5][(j * 4 + 1) % 5] = v.y;
                    wreg[p][(j * 4 + 2) / 5][(j * 4 + 2) % 5] = v.z;
                    wreg[p][(j * 4 + 3) / 5][(j * 4 + 3) % 5] = v.w;
                }
            }
        }
        float breg[LL];
#pragma unroll
        for (int l = 0; l < LL; ++l) breg[l] = bias[l];

        const float* xb = x + ((size_t)n * TT + t0) * DD;
        float* lb = logits + ((size_t)n * TT + t0) * LL;

#pragma unroll
        for (int pp = 0; pp < 4; ++pp) {
            const int iA = 2 * pp;
            if (iA >= nact) break;             // wave-uniform
            const int iB = iA + 1;
            const bool aB = (iB < nact);       // wave-uniform

            const floatx4* xpA = reinterpret_cast<const floatx4*>(xb + (size_t)iA * DD);
            const floatx4* xpB = reinterpret_cast<const floatx4*>(xb + (size_t)iB * DD);
            floatx4 vA[3], vB[3];
#pragma unroll
            for (int p = 0; p < 3; ++p) vA[p] = xpA[p * 64 + lane];
            if (aB) {
#pragma unroll
                for (int p = 0; p < 3; ++p) vB[p] = xpB[p * 64 + lane];
            }

            float accA[LL] = {0.f, 0.f, 0.f, 0.f, 0.f};
            float accB[LL] = {0.f, 0.f, 0.f, 0.f, 0.f};
#pragma unroll
            for (int p = 0; p < 3; ++p) {
#pragma unroll
                for (int l = 0; l < LL; ++l) {
                    accA[l] += vA[p].x * wreg[p][0][l] + vA[p].y * wreg[p][1][l] +
                               vA[p].z * wreg[p][2][l] + vA[p].w * wreg[p][3][l];
                }
            }
            if (aB) {
#pragma unroll
                for (int p = 0; p < 3; ++p) {
#pragma unroll
                    for (int l = 0; l < LL; ++l) {
                        accB[l] += vB[p].x * wreg[p][0][l] + vB[p].y * wreg[p][1][l] +
                                   vB[p].z * wreg[p][2][l] + vB[p].w * wreg[p][3][l];
                    }
                }
            }

#pragma unroll
            for (int l = 0; l < LL; ++l) accA[l] = wave_sum_dpp(accA[l]);
            if (aB) {
#pragma unroll
                for (int l = 0; l < LL; ++l) accB[l] = wave_sum_dpp(accB[l]);
            }

            if (lane == 63) {
#pragma unroll
                for (int l = 0; l < LL; ++l) lb[(size_t)iA * LL + l] = accA[l] + breg[l];
                if (aB) {
#pragma unroll
                    for (int l = 0; l < LL; ++l) lb[(size_t)iB * LL + l] = accB[l] + breg[l];
                }
            }
        }
        if (lane == 63) {
            __threadfence();
            __hip_atomic_fetch_add(&seqflag[n], 1, __ATOMIC_RELEASE, __HIP_MEMORY_SCOPE_AGENT);
        }
        return;
    }

    // ================= scan consumer =================
    const int sbid = bid - 1024;               // 0..191

    if (sbid < 128) {
        const int n  = sbid;
        const int sl = seqlen[n & (BB - 1)];
        const int expect = (sl + 7) >> 3;
        if (tid == 0) {
            while (__hip_atomic_load(&seqflag[n], __ATOMIC_ACQUIRE, __HIP_MEMORY_SCOPE_AGENT) < expect) {}
            __threadfence();
        }
        if (tid < 25) { const float tv = trans[tid]; s_tr[tid] = tv; s_etr[tid] = __expf(tv); }
        __syncthreads();

        const float* lg = logits + (size_t)n * TT * LL;
        const int lim = sl * LL;
        for (int i = tid; i < lim; i += 512) s_lg[0][i] = lg[i];
        __syncthreads();

        {
            const bool sec = (n >= BB);
            const int* lab = label + (n & (BB - 1)) * TT;
            const int t = tid;
            float sc = 0.f;
            if (t < sl) {
                const int lv = lab[t];
                const int tg = (lv > 0) ? (sec ? lv + 1 : 1) : 0;
                sc = s_lg[0][t * 5 + tg];
                if (t >= 1) {
                    const int lp = lab[t - 1];
                    const int tp = (lp > 0) ? (sec ? lp + 1 : 1) : 0;
                    sc += s_tr[tp * 5 + tg];
                }
            }
#pragma unroll
            for (int off = 32; off > 0; off >>= 1) sc += __shfl_xor(sc, off, 64);
            if ((tid & 63) == 0) s_ws[tid >> 6] = sc;
        }

        if (tid < 320) {
            const int c = tid / 5, r = tid - 5 * c;
            float p[5];
#pragma unroll
            for (int j = 0; j < 5; ++j) p[j] = (j == r) ? 0.f : NEG_INF;
#pragma unroll
            for (int i = 0; i < 8; ++i) {
                const int t = c * 8 + 1 + i;
                const bool act = t < sl;
                const float m = fmaxf(fmaxf(fmaxf(p[0], p[1]), fmaxf(p[2], p[3])), p[4]);
                float e[5];
#pragma unroll
                for (int k = 0; k < 5; ++k) e[k] = __expf(p[k] - m);
                float nv[5];
#pragma unroll
                for (int j = 0; j < 5; ++j) {
                    float s = e[0] * s_etr[j];
#pragma unroll
                    for (int k = 1; k < 5; ++k) s += e[k] * s_etr[k * 5 + j];
                    nv[j] = m + __logf(s) + s_lg[0][t * 5 + j];
                }
#pragma unroll
                for (int j = 0; j < 5; ++j) p[j] = act ? nv[j] : p[j];
            }
#pragma unroll
            for (int j = 0; j < 5; ++j) s_P[c * 25 + r * 5 + j] = p[j];
        }
        __syncthreads();

#pragma unroll
        for (int lev = 0; lev < 6; ++lev) {
            const int np = 32 >> lev;
            const float* inb = (lev & 1) ? s_Q : s_P;
            float* outb      = (lev & 1) ? s_P : s_Q;
            for (int task = tid; task < np * 25; task += 512) {
                const int pm = task / 25;
                const int e  = task - pm * 25;
                const int r  = e / 5, j = e - 5 * r;
                const float* A  = inb + (2 * pm) * 25;
                const float* Bm = inb + (2 * pm + 1) * 25;
                float v[5];
#pragma unroll
                for (int k = 0; k < 5; ++k) v[k] = A[r * 5 + k] + Bm[k * 5 + j];
                float m = fmaxf(fmaxf(fmaxf(v[0], v[1]), fmaxf(v[2], v[3])), v[4]);
                float ssum = 0.f;
#pragma unroll
                for (int k = 0; k < 5; ++k) ssum += __expf(v[k] - m);
                outb[pm * 25 + e] = m + __logf(ssum);
            }
            __syncthreads();
        }

        if (tid == 0) {
            float b[5];
#pragma unroll
            for (int j = 0; j < 5; ++j) {
                float v[5];
#pragma unroll
                for (int k = 0; k < 5; ++k) v[k] = s_lg[0][k] + s_P[k * 5 + j];
                float m = fmaxf(fmaxf(fmaxf(v[0], v[1]), fmaxf(v[2], v[3])), v[4]);
                float ssum = 0.f;
#pragma unroll
                for (int k = 0; k < 5; ++k) ssum += __expf(v[k] - m);
                b[j] = m + __logf(ssum);
            }
            float m = fmaxf(fmaxf(fmaxf(b[0], b[1]), fmaxf(b[2], b[3])), b[4]);
            float ssum = 0.f;
#pragma unroll
            for (int j = 0; j < 5; ++j) ssum += __expf(b[j] - m);
            const float ln = m + __logf(ssum);
            float sc = 0.f;
#pragma unroll
            for (int wv = 0; wv < 8; ++wv) sc += s_ws[wv];
            losspart[n] = ln - sc;
        }
    } else {
        const int bb = sbid - 128;
        const int sl = seqlen[bb];
        const int expect = (sl + 7) >> 3;
        if (tid == 0) {
            while (__hip_atomic_load(&seqflag[bb], __ATOMIC_ACQUIRE, __HIP_MEMORY_SCOPE_AGENT) < expect) {}
            while (__hip_atomic_load(&seqflag[bb + BB], __ATOMIC_ACQUIRE, __HIP_MEMORY_SCOPE_AGENT) < expect) {}
            __threadfence();
        }
        if (tid < 25) s_tr[tid] = trans[tid];
        __syncthreads();

        const float* lgA = logits + (size_t)bb * TT * LL;
        const float* lgB = logits + (size_t)(bb + BB) * TT * LL;
        {
            const int lim = sl * LL;
            for (int i = tid; i < lim; i += 512) { s_lg[0][i] = lgA[i]; s_lg[1][i] = lgB[i]; }
        }
        __syncthreads();

        const int sid = tid / 160;
        const int rem = tid - sid * 160;
        const int cc  = rem / 5;
        const int rr  = rem - cc * 5;

        if (tid < 320) {
            float p[5];
#pragma unroll
            for (int j = 0; j < 5; ++j) p[j] = (j == rr) ? 0.f : NEG_INF;
#pragma unroll
            for (int i = 0; i < 16; ++i) {
                const int t = cc * 16 + 1 + i;
                const bool act = t < sl;
                float nv[5];
#pragma unroll
                for (int j = 0; j < 5; ++j) {
                    float b = p[0] + s_tr[j];
#pragma unroll
                    for (int k = 1; k < 5; ++k) b = fmaxf(b, p[k] + s_tr[k * 5 + j]);
                    nv[j] = b + s_lg[sid][t * 5 + j];
                }
#pragma unroll
                for (int j = 0; j < 5; ++j) p[j] = act ? nv[j] : p[j];
            }
#pragma unroll
            for (int j = 0; j < 5; ++j) s_P[sid * 800 + cc * 25 + rr * 5 + j] = p[j];
        }
        __syncthreads();

#pragma unroll
        for (int st = 1; st < 32; st <<= 1) {
            float Ar[5], Bm[25];
            const bool doit = (tid < 320) && (cc >= st);
            if (doit) {
#pragma unroll
                for (int k = 0; k < 5; ++k) Ar[k] = s_P[sid * 800 + (cc - st) * 25 + rr * 5 + k];
#pragma unroll
                for (int e = 0; e < 25; ++e) Bm[e] = s_P[sid * 800 + cc * 25 + e];
            }
            __syncthreads();
            if (doit) {
#pragma unroll
                for (int j = 0; j < 5; ++j) {
                    float b = Ar[0] + Bm[j];
#pragma unroll
                    for (int k = 1; k < 5; ++k) b = fmaxf(b, Ar[k] + Bm[k * 5 + j]);
                    s_P[sid * 800 + cc * 25 + rr * 5 + j] = b;
                }
            }
            __syncthreads();
        }

        if (tid < 320) {
            float b = s_lg[sid][0] + s_P[sid * 800 + cc * 25 + rr];
#pragma unroll
            for (int k = 1; k < 5; ++k)
                b = fmaxf(b, s_lg[sid][k] + s_P[sid * 800 + cc * 25 + k * 5 + rr]);
            s_A[sid][(cc + 1) * 5 + rr] = b;
        } else if (tid < 330) {
            const int i2 = tid - 320;
            const int s = i2 / 5, j = i2 - 5 * s;
            s_A[s][j] = s_lg[s][j];
        }
        __syncthreads();

        unsigned bpw[16];
        const int vs = tid >> 5, vc = tid & 31;
        if (tid < 64) {
            float a[5];
#pragma unroll
            for (int j = 0; j < 5; ++j) a[j] = s_A[vs][vc * 5 + j];
#pragma unroll
            for (int i = 0; i < 16; ++i) {
                const int t = vc * 16 + 1 + i;
                const bool act = t < sl;
                float nv[5]; int gi[5];
#pragma unroll
                for (int j = 0; j < 5; ++j) {
                    float b = a[0] + s_tr[j]; int g = 0;
#pragma unroll
                    for (int k = 1; k < 5; ++k) {
                        const float cn = a[k] + s_tr[k * 5 + j];
                        if (cn > b) { b = cn; g = k; }
                    }
                    nv[j] = b + s_lg[vs][t * 5 + j]; gi[j] = g;
                }
                const unsigned wv = (unsigned)gi[0] | ((unsigned)gi[1] << 3) |
                                    ((unsigned)gi[2] << 6) | ((unsigned)gi[3] << 9) |
                                    ((unsigned)gi[4] << 12);
                bpw[i] = act ? wv : IDENT_W;
#pragma unroll
                for (int j = 0; j < 5; ++j) a[j] = act ? nv[j] : a[j];
            }
            int m[5] = {0, 1, 2, 3, 4};
#pragma unroll
            for (int i = 15; i >= 0; --i) {
                const unsigned wv = bpw[i];
#pragma unroll
                for (int j = 0; j < 5; ++j) m[j] = (int)((wv >> (3 * m[j])) & 7u);
            }
            s_mapw[vs][vc] = (unsigned)m[0] | ((unsigned)m[1] << 3) | ((unsigned)m[2] << 6) |
                             ((unsigned)m[3] << 9) | ((unsigned)m[4] << 12);
        }
        __syncthreads();

        if (tid < 2) {
            const int s = tid;
            float b = s_A[s][32 * 5 + 0]; int lt = 0;
#pragma unroll
            for (int j = 1; j < 5; ++j) {
                const float cn = s_A[s][32 * 5 + j];
                if (cn > b) { b = cn; lt = j; }
            }
            unsigned wv[32];
#pragma unroll
            for (int c = 0; c < 32; ++c) wv[c] = s_mapw[s][c];
            int bc = lt; s_B[s][32] = lt;
#pragma unroll
            for (int c = 31; c >= 0; --c) { bc = (int)((wv[c] >> (3 * bc)) & 7u); s_B[s][c] = bc; }
        }
        __syncthreads();

        if (tid < 64) {
            int cur = s_B[vs][vc + 1];
#pragma unroll
            for (int i = 15; i >= 0; --i) {
                cur = (int)((bpw[i] >> (3 * cur)) & 7u);
                s_tags[vs][vc * 16 + i] = cur;
            }
        }
        __syncthreads();

        {
            const int t = tid;
            const int* lab = label + bb * TT;
            const int t1 = s_tags[0][t];
            const int t2 = s_tags[1][t];
            const int vit = (t1 == 0 || t2 == 0) ? 0 : (t2 - 1);
            out[bb * TT + t] = (float)vit;
            int ok = ((vit == lab[t]) && (t < sl)) ? 1 : 0;
#pragma unroll
            for (int off = 32; off > 0; off >>= 1) ok += __shfl_xor(ok, off, 64);
            if ((tid & 63) == 0) s_wok[tid >> 6] = ok;
        }
        __syncthreads();
        if (tid == 0) {
            int ok = 0;
#pragma unroll
            for (int wv = 0; wv < 8; ++wv) ok += s_wok[wv];
            okpart[bb] = ok;
        }
    }

    // ---- folded final: last scan block reduces losspart/okpart ----
    __syncthreads();
    if (tid == 0) {
        __threadfence();
        s_last = (atomicAdd(ctr, 1) == 191) ? 1 : 0;
    }
    __syncthreads();
    if (s_last && tid < 64) {
        __threadfence();
        float f = __hip_atomic_load(&losspart[tid], __ATOMIC_RELAXED, __HIP_MEMORY_SCOPE_AGENT) +
                  __hip_atomic_load(&losspart[tid + 64], __ATOMIC_RELAXED, __HIP_MEMORY_SCOPE_AGENT);
        int ok = __hip_atomic_load(&okpart[tid], __ATOMIC_RELAXED, __HIP_MEMORY_SCOPE_AGENT);
        int sl = seqlen[tid];
#pragma unroll
        for (int off = 32; off > 0; off >>= 1) {
            f  += __shfl_xor(f, off, 64);
            ok += __shfl_xor(ok, off, 64);
            sl += __shfl_xor(sl, off, 64);
        }
        if (tid == 0) {
            out[BB * TT]     = f / (float)NSEQ;
            out[BB * TT + 1] = (float)ok / (float)sl;
        }
    }
}

// ---------------------------------------------------------------------------
extern "C" void kernel_launch(void* const* d_in, const int* in_sizes, int n_in,
                              void* d_out, int out_size, void* d_ws, size_t ws_size,
                              hipStream_t stream) {
    const float* x      = (const float*)d_in[0];
    const int*   label  = (const int*)d_in[1];
    const int*   seqlen = (const int*)d_in[2];
    const float* W      = (const float*)d_in[3];
    const float* bias   = (const float*)d_in[4];
    const float* trans  = (const float*)d_in[5];
    float* out = (float*)d_out;
    char*  ws  = (char*)d_ws;

    float* ws_logits   = (float*)(ws);                // 1,310,720 B
    float* ws_losspart = (float*)(ws + 1310720);      // 512 B
    int*   ws_okpart   = (int*)(ws + 1311232);        // 256 B
    int*   ws_ctr      = (int*)(ws + 1311488);        // 4 B
    int*   ws_seqflag  = (int*)(ws + 1311744);        // 512 B
    // zero ctr + seqflag in one memset (graph-legal)
    (void)hipMemsetAsync(ws + 1311488, 0, 768, stream);

    hipLaunchKernelGGL(k_all, dim3(1216), dim3(512), 0, stream,
                       x, label, seqlen, W, bias, trans,
                       ws_logits, out, ws_losspart, ws_okpart, ws_ctr, ws_seqflag);
}

// Round 23
// 44.637 us; speedup vs baseline: 10.2980x; 10.2980x over previous
//
#include <hip/hip_runtime.h>

#define BB 64
#define TT 512
#define DD 768
#define LL 5
#define NSEQ 128
#define NTOK 65536
#define NEG_INF (-1e30f)
#define IDENT_W 0x4688u   // bp word encoding j->j (0|1<<3|2<<6|3<<9|4<<12)

typedef float floatx4 __attribute__((ext_vector_type(4)));

// Wave64 sum via DPP on the VALU pipe. Result valid in lane 63.
__device__ __forceinline__ float wave_sum_dpp(float v) {
    int t;
    t = __builtin_amdgcn_update_dpp(0, __float_as_int(v), 0x111, 0xf, 0xf, false);
    v += __int_as_float(t);
    t = __builtin_amdgcn_update_dpp(0, __float_as_int(v), 0x112, 0xf, 0xf, false);
    v += __int_as_float(t);
    t = __builtin_amdgcn_update_dpp(0, __float_as_int(v), 0x114, 0xf, 0xf, false);
    v += __int_as_float(t);
    t = __builtin_amdgcn_update_dpp(0, __float_as_int(v), 0x118, 0xf, 0xf, false);
    v += __int_as_float(t);
    t = __builtin_amdgcn_update_dpp(0, __float_as_int(v), 0x142, 0xa, 0xf, false);
    v += __int_as_float(t);
    t = __builtin_amdgcn_update_dpp(0, __float_as_int(v), 0x143, 0xc, 0xf, false);
    v += __int_as_float(t);
    return v;
}

// ---------------------------------------------------------------------------
// Kernel A: logits = x @ W + b. R16 config exactly (best measured: 39.7 us
// total): balanced slot mapping, W via coalesced float4, pair-ILP, DPP
// reduction. No nt-loads (R21: -10us), no flags.
// ---------------------------------------------------------------------------
__global__ __launch_bounds__(256) void k_logits(const float* __restrict__ x,
                                                const float* __restrict__ W,
                                                const float* __restrict__ bias,
                                                const int* __restrict__ seqlen,
                                                float* __restrict__ logits) {
    const int lane = threadIdx.x & 63;
    const int w    = blockIdx.x * 4 + (threadIdx.x >> 6);   // 0..8191
    const int n    = w & 127;
    const int slot = w >> 7;                                // 0..63
    const int sl   = seqlen[n & (BB - 1)];
    if (slot >= sl) return;

    float wreg[3][4][LL];
    {
        const floatx4* W4 = reinterpret_cast<const floatx4*>(W);
#pragma unroll
        for (int p = 0; p < 3; ++p) {
            const int base4 = p * 320 + lane * 5;
#pragma unroll
            for (int j = 0; j < 5; ++j) {
                const floatx4 v = W4[base4 + j];
                wreg[p][(j * 4 + 0) / 5][(j * 4 + 0) % 5] = v.x;
                wreg[p][(j * 4 + 1) / 5][(j * 4 + 1) % 5] = v.y;
                wreg[p][(j * 4 + 2) / 5][(j * 4 + 2) % 5] = v.z;
                wreg[p][(j * 4 + 3) / 5][(j * 4 + 3) % 5] = v.w;
            }
        }
    }
    float breg[LL];
#pragma unroll
    for (int l = 0; l < LL; ++l) breg[l] = bias[l];

    const float* xb = x + (size_t)n * TT * DD;
    float* lb = logits + (size_t)n * TT * LL;

#pragma unroll
    for (int pp = 0; pp < 4; ++pp) {
        const int tA = slot + 128 * pp;
        if (tA >= sl) break;                   // wave-uniform
        const int tB = tA + 64;
        const bool aB = (tB < sl);             // wave-uniform

        const floatx4* xpA = reinterpret_cast<const floatx4*>(xb + (size_t)tA * DD);
        const floatx4* xpB = reinterpret_cast<const floatx4*>(xb + (size_t)tB * DD);
        floatx4 vA[3], vB[3];
#pragma unroll
        for (int p = 0; p < 3; ++p) vA[p] = xpA[p * 64 + lane];
        if (aB) {
#pragma unroll
            for (int p = 0; p < 3; ++p) vB[p] = xpB[p * 64 + lane];
        }

        float accA[LL] = {0.f, 0.f, 0.f, 0.f, 0.f};
        float accB[LL] = {0.f, 0.f, 0.f, 0.f, 0.f};
#pragma unroll
        for (int p = 0; p < 3; ++p) {
#pragma unroll
            for (int l = 0; l < LL; ++l) {
                accA[l] += vA[p].x * wreg[p][0][l] + vA[p].y * wreg[p][1][l] +
                           vA[p].z * wreg[p][2][l] + vA[p].w * wreg[p][3][l];
            }
        }
        if (aB) {
#pragma unroll
            for (int p = 0; p < 3; ++p) {
#pragma unroll
                for (int l = 0; l < LL; ++l) {
                    accB[l] += vB[p].x * wreg[p][0][l] + vB[p].y * wreg[p][1][l] +
                               vB[p].z * wreg[p][2][l] + vB[p].w * wreg[p][3][l];
                }
            }
        }

#pragma unroll
        for (int l = 0; l < LL; ++l) accA[l] = wave_sum_dpp(accA[l]);
        if (aB) {
#pragma unroll
            for (int l = 0; l < LL; ++l) accB[l] = wave_sum_dpp(accB[l]);
        }

        if (lane == 63) {
#pragma unroll
            for (int l = 0; l < LL; ++l) lb[(size_t)tA * LL + l] = accA[l] + breg[l];
            if (aB) {
#pragma unroll
                for (int l = 0; l < LL; ++l) lb[(size_t)tB * LL + l] = accB[l] + breg[l];
            }
        }
    }
}

// ---------------------------------------------------------------------------
// Kernel B: role-split scan + FOLDED final scalars (last-block-done).
// ---------------------------------------------------------------------------
__global__ __launch_bounds__(512) void k_scan4(const float* __restrict__ logits,
                                               const int* __restrict__ label,
                                               const int* __restrict__ seqlen,
                                               const float* __restrict__ trans,
                                               float* __restrict__ out,
                                               float* __restrict__ losspart,
                                               int* __restrict__ okpart,
                                               int* __restrict__ ctr) {
    __shared__ float s_lg[2][TT * LL + 8];
    __shared__ float s_P[1600];
    __shared__ float s_Q[800];
    __shared__ float s_A[2][33 * 5];
    __shared__ float s_tr[25];
    __shared__ float s_etr[25];
    __shared__ unsigned s_mapw[2][32];
    __shared__ int s_B[2][33];
    __shared__ int s_tags[2][TT];
    __shared__ float s_ws[8];
    __shared__ int s_wok[8];
    __shared__ int s_last;

    const int tid = threadIdx.x;
    const int bid = blockIdx.x;

    if (bid < 128) {
        const int n  = bid;
        const int sl = seqlen[n & (BB - 1)];
        const float* lg = logits + (size_t)n * TT * LL;
        if (tid < 25) { const float tv = trans[tid]; s_tr[tid] = tv; s_etr[tid] = __expf(tv); }
        const int lim = sl * LL;
        for (int i = tid; i < lim; i += 512) s_lg[0][i] = lg[i];
        __syncthreads();

        {
            const bool sec = (n >= BB);
            const int* lab = label + (n & (BB - 1)) * TT;
            const int t = tid;
            float sc = 0.f;
            if (t < sl) {
                const int lv = lab[t];
                const int tg = (lv > 0) ? (sec ? lv + 1 : 1) : 0;
                sc = s_lg[0][t * 5 + tg];
                if (t >= 1) {
                    const int lp = lab[t - 1];
                    const int tp = (lp > 0) ? (sec ? lp + 1 : 1) : 0;
                    sc += s_tr[tp * 5 + tg];
                }
            }
#pragma unroll
            for (int off = 32; off > 0; off >>= 1) sc += __shfl_xor(sc, off, 64);
            if ((tid & 63) == 0) s_ws[tid >> 6] = sc;
        }

        if (tid < 320) {
            const int c = tid / 5, r = tid - 5 * c;
            float p[5];
#pragma unroll
            for (int j = 0; j < 5; ++j) p[j] = (j == r) ? 0.f : NEG_INF;
#pragma unroll
            for (int i = 0; i < 8; ++i) {
                const int t = c * 8 + 1 + i;
                const bool act = t < sl;
                const float m = fmaxf(fmaxf(fmaxf(p[0], p[1]), fmaxf(p[2], p[3])), p[4]);
                float e[5];
#pragma unroll
                for (int k = 0; k < 5; ++k) e[k] = __expf(p[k] - m);
                float nv[5];
#pragma unroll
                for (int j = 0; j < 5; ++j) {
                    float s = e[0] * s_etr[j];
#pragma unroll
                    for (int k = 1; k < 5; ++k) s += e[k] * s_etr[k * 5 + j];
                    nv[j] = m + __logf(s) + s_lg[0][t * 5 + j];
                }
#pragma unroll
                for (int j = 0; j < 5; ++j) p[j] = act ? nv[j] : p[j];
            }
#pragma unroll
            for (int j = 0; j < 5; ++j) s_P[c * 25 + r * 5 + j] = p[j];
        }
        __syncthreads();

#pragma unroll
        for (int lev = 0; lev < 6; ++lev) {
            const int np = 32 >> lev;
            const float* inb = (lev & 1) ? s_Q : s_P;
            float* outb      = (lev & 1) ? s_P : s_Q;
            for (int task = tid; task < np * 25; task += 512) {
                const int pm = task / 25;
                const int e  = task - pm * 25;
                const int r  = e / 5, j = e - 5 * r;
                const float* A  = inb + (2 * pm) * 25;
                const float* Bm = inb + (2 * pm + 1) * 25;
                float v[5];
#pragma unroll
                for (int k = 0; k < 5; ++k) v[k] = A[r * 5 + k] + Bm[k * 5 + j];
                float m = fmaxf(fmaxf(fmaxf(v[0], v[1]), fmaxf(v[2], v[3])), v[4]);
                float ssum = 0.f;
#pragma unroll
                for (int k = 0; k < 5; ++k) ssum += __expf(v[k] - m);
                outb[pm * 25 + e] = m + __logf(ssum);
            }
            __syncthreads();
        }

        if (tid == 0) {
            float b[5];
#pragma unroll
            for (int j = 0; j < 5; ++j) {
                float v[5];
#pragma unroll
                for (int k = 0; k < 5; ++k) v[k] = s_lg[0][k] + s_P[k * 5 + j];
                float m = fmaxf(fmaxf(fmaxf(v[0], v[1]), fmaxf(v[2], v[3])), v[4]);
                float ssum = 0.f;
#pragma unroll
                for (int k = 0; k < 5; ++k) ssum += __expf(v[k] - m);
                b[j] = m + __logf(ssum);
            }
            float m = fmaxf(fmaxf(fmaxf(b[0], b[1]), fmaxf(b[2], b[3])), b[4]);
            float ssum = 0.f;
#pragma unroll
            for (int j = 0; j < 5; ++j) ssum += __expf(b[j] - m);
            const float ln = m + __logf(ssum);
            float sc = 0.f;
#pragma unroll
            for (int wv = 0; wv < 8; ++wv) sc += s_ws[wv];
            losspart[n] = ln - sc;
        }
    } else {
        const int bb = bid - 128;
        const int sl = seqlen[bb];
        const float* lgA = logits + (size_t)bb * TT * LL;
        const float* lgB = logits + (size_t)(bb + BB) * TT * LL;

        if (tid < 25) s_tr[tid] = trans[tid];
        {
            const int lim = sl * LL;
            for (int i = tid; i < lim; i += 512) { s_lg[0][i] = lgA[i]; s_lg[1][i] = lgB[i]; }
        }
        __syncthreads();

        const int sid = tid / 160;
        const int rem = tid - sid * 160;
        const int cc  = rem / 5;
        const int rr  = rem - cc * 5;

        if (tid < 320) {
            float p[5];
#pragma unroll
            for (int j = 0; j < 5; ++j) p[j] = (j == rr) ? 0.f : NEG_INF;
#pragma unroll
            for (int i = 0; i < 16; ++i) {
                const int t = cc * 16 + 1 + i;
                const bool act = t < sl;
                float nv[5];
#pragma unroll
                for (int j = 0; j < 5; ++j) {
                    float b = p[0] + s_tr[j];
#pragma unroll
                    for (int k = 1; k < 5; ++k) b = fmaxf(b, p[k] + s_tr[k * 5 + j]);
                    nv[j] = b + s_lg[sid][t * 5 + j];
                }
#pragma unroll
                for (int j = 0; j < 5; ++j) p[j] = act ? nv[j] : p[j];
            }
#pragma unroll
            for (int j = 0; j < 5; ++j) s_P[sid * 800 + cc * 25 + rr * 5 + j] = p[j];
        }
        __syncthreads();

#pragma unroll
        for (int st = 1; st < 32; st <<= 1) {
            float Ar[5], Bm[25];
            const bool doit = (tid < 320) && (cc >= st);
            if (doit) {
#pragma unroll
                for (int k = 0; k < 5; ++k) Ar[k] = s_P[sid * 800 + (cc - st) * 25 + rr * 5 + k];
#pragma unroll
                for (int e = 0; e < 25; ++e) Bm[e] = s_P[sid * 800 + cc * 25 + e];
            }
            __syncthreads();
            if (doit) {
#pragma unroll
                for (int j = 0; j < 5; ++j) {
                    float b = Ar[0] + Bm[j];
#pragma unroll
                    for (int k = 1; k < 5; ++k) b = fmaxf(b, Ar[k] + Bm[k * 5 + j]);
                    s_P[sid * 800 + cc * 25 + rr * 5 + j] = b;
                }
            }
            __syncthreads();
        }

        if (tid < 320) {
            float b = s_lg[sid][0] + s_P[sid * 800 + cc * 25 + rr];
#pragma unroll
            for (int k = 1; k < 5; ++k)
                b = fmaxf(b, s_lg[sid][k] + s_P[sid * 800 + cc * 25 + k * 5 + rr]);
            s_A[sid][(cc + 1) * 5 + rr] = b;
        } else if (tid < 330) {
            const int i2 = tid - 320;
            const int s = i2 / 5, j = i2 - 5 * s;
            s_A[s][j] = s_lg[s][j];
        }
        __syncthreads();

        unsigned bpw[16];
        const int vs = tid >> 5, vc = tid & 31;
        if (tid < 64) {
            float a[5];
#pragma unroll
            for (int j = 0; j < 5; ++j) a[j] = s_A[vs][vc * 5 + j];
#pragma unroll
            for (int i = 0; i < 16; ++i) {
                const int t = vc * 16 + 1 + i;
                const bool act = t < sl;
                float nv[5]; int gi[5];
#pragma unroll
                for (int j = 0; j < 5; ++j) {
                    float b = a[0] + s_tr[j]; int g = 0;
#pragma unroll
                    for (int k = 1; k < 5; ++k) {
                        const float cn = a[k] + s_tr[k * 5 + j];
                        if (cn > b) { b = cn; g = k; }
                    }
                    nv[j] = b + s_lg[vs][t * 5 + j]; gi[j] = g;
                }
                const unsigned wv = (unsigned)gi[0] | ((unsigned)gi[1] << 3) |
                                    ((unsigned)gi[2] << 6) | ((unsigned)gi[3] << 9) |
                                    ((unsigned)gi[4] << 12);
                bpw[i] = act ? wv : IDENT_W;
#pragma unroll
                for (int j = 0; j < 5; ++j) a[j] = act ? nv[j] : a[j];
            }
            int m[5] = {0, 1, 2, 3, 4};
#pragma unroll
            for (int i = 15; i >= 0; --i) {
                const unsigned wv = bpw[i];
#pragma unroll
                for (int j = 0; j < 5; ++j) m[j] = (int)((wv >> (3 * m[j])) & 7u);
            }
            s_mapw[vs][vc] = (unsigned)m[0] | ((unsigned)m[1] << 3) | ((unsigned)m[2] << 6) |
                             ((unsigned)m[3] << 9) | ((unsigned)m[4] << 12);
        }
        __syncthreads();

        if (tid < 2) {
            const int s = tid;
            float b = s_A[s][32 * 5 + 0]; int lt = 0;
#pragma unroll
            for (int j = 1; j < 5; ++j) {
                const float cn = s_A[s][32 * 5 + j];
                if (cn > b) { b = cn; lt = j; }
            }
            unsigned wv[32];
#pragma unroll
            for (int c = 0; c < 32; ++c) wv[c] = s_mapw[s][c];
            int bc = lt; s_B[s][32] = lt;
#pragma unroll
            for (int c = 31; c >= 0; --c) { bc = (int)((wv[c] >> (3 * bc)) & 7u); s_B[s][c] = bc; }
        }
        __syncthreads();

        if (tid < 64) {
            int cur = s_B[vs][vc + 1];
#pragma unroll
            for (int i = 15; i >= 0; --i) {
                cur = (int)((bpw[i] >> (3 * cur)) & 7u);
                s_tags[vs][vc * 16 + i] = cur;
            }
        }
        __syncthreads();

        {
            const int t = tid;
            const int* lab = label + bb * TT;
            const int t1 = s_tags[0][t];
            const int t2 = s_tags[1][t];
            const int vit = (t1 == 0 || t2 == 0) ? 0 : (t2 - 1);
            out[bb * TT + t] = (float)vit;
            int ok = ((vit == lab[t]) && (t < sl)) ? 1 : 0;
#pragma unroll
            for (int off = 32; off > 0; off >>= 1) ok += __shfl_xor(ok, off, 64);
            if ((tid & 63) == 0) s_wok[tid >> 6] = ok;
        }
        __syncthreads();
        if (tid == 0) {
            int ok = 0;
#pragma unroll
            for (int wv = 0; wv < 8; ++wv) ok += s_wok[wv];
            okpart[bb] = ok;
        }
    }

    // ---- folded final: last block reduces losspart/okpart -> scalars ----
    __syncthreads();
    if (tid == 0) {
        __threadfence();
        s_last = (atomicAdd(ctr, 1) == 191) ? 1 : 0;
    }
    __syncthreads();
    if (s_last && tid < 64) {
        __threadfence();
        float f = __hip_atomic_load(&losspart[tid], __ATOMIC_RELAXED, __HIP_MEMORY_SCOPE_AGENT) +
                  __hip_atomic_load(&losspart[tid + 64], __ATOMIC_RELAXED, __HIP_MEMORY_SCOPE_AGENT);
        int ok = __hip_atomic_load(&okpart[tid], __ATOMIC_RELAXED, __HIP_MEMORY_SCOPE_AGENT);
        int sl = seqlen[tid];
#pragma unroll
        for (int off = 32; off > 0; off >>= 1) {
            f  += __shfl_xor(f, off, 64);
            ok += __shfl_xor(ok, off, 64);
            sl += __shfl_xor(sl, off, 64);
        }
        if (tid == 0) {
            out[BB * TT]     = f / (float)NSEQ;
            out[BB * TT + 1] = (float)ok / (float)sl;
        }
    }
}

// ---------------------------------------------------------------------------
extern "C" void kernel_launch(void* const* d_in, const int* in_sizes, int n_in,
                              void* d_out, int out_size, void* d_ws, size_t ws_size,
                              hipStream_t stream) {
    const float* x      = (const float*)d_in[0];
    const int*   label  = (const int*)d_in[1];
    const int*   seqlen = (const int*)d_in[2];
    const float* W      = (const float*)d_in[3];
    const float* bias   = (const float*)d_in[4];
    const float* trans  = (const float*)d_in[5];
    float* out = (float*)d_out;
    char*  ws  = (char*)d_ws;

    float* ws_logits   = (float*)(ws);                // 1,310,720 B
    float* ws_losspart = (float*)(ws + 1310720);      // 512 B
    int*   ws_okpart   = (int*)(ws + 1311232);        // 256 B
    int*   ws_ctr      = (int*)(ws + 1311488);        // 4 B (zeroed per call)

    (void)hipMemsetAsync(ws_ctr, 0, 4, stream);
    hipLaunchKernelGGL(k_logits, dim3(2048), dim3(256), 0, stream,
                       x, W, bias, seqlen, ws_logits);
    hipLaunchKernelGGL(k_scan4, dim3(192), dim3(512), 0, stream,
                       ws_logits, label, seqlen, trans, out, ws_losspart,
                       ws_okpart, ws_ctr);
}

// Round 24
// 39.382 us; speedup vs baseline: 11.6721x; 1.1334x over previous
//
#include <hip/hip_runtime.h>

#define BB 64
#define TT 512
#define DD 768
#define LL 5
#define NSEQ 128
#define NTOK 65536
#define NEG_INF (-1e30f)
#define IDENT_W 0x4688u   // bp word encoding j->j (0|1<<3|2<<6|3<<9|4<<12)

// Wave64 sum via DPP on the VALU pipe. Result valid in lane 63.
__device__ __forceinline__ float wave_sum_dpp(float v) {
    int t;
    t = __builtin_amdgcn_update_dpp(0, __float_as_int(v), 0x111, 0xf, 0xf, false);
    v += __int_as_float(t);
    t = __builtin_amdgcn_update_dpp(0, __float_as_int(v), 0x112, 0xf, 0xf, false);
    v += __int_as_float(t);
    t = __builtin_amdgcn_update_dpp(0, __float_as_int(v), 0x114, 0xf, 0xf, false);
    v += __int_as_float(t);
    t = __builtin_amdgcn_update_dpp(0, __float_as_int(v), 0x118, 0xf, 0xf, false);
    v += __int_as_float(t);
    t = __builtin_amdgcn_update_dpp(0, __float_as_int(v), 0x142, 0xa, 0xf, false);
    v += __int_as_float(t);
    t = __builtin_amdgcn_update_dpp(0, __float_as_int(v), 0x143, 0xc, 0xf, false);
    v += __int_as_float(t);
    return v;
}

// ---------------------------------------------------------------------------
// Kernel A: logits = x @ W + b. Best-measured config (R16, 39.7us total):
// balanced slot mapping, W via coalesced float4, pair-ILP, DPP reduction.
// ---------------------------------------------------------------------------
__global__ __launch_bounds__(256) void k_logits(const float* __restrict__ x,
                                                const float* __restrict__ W,
                                                const float* __restrict__ bias,
                                                const int* __restrict__ seqlen,
                                                float* __restrict__ logits) {
    const int lane = threadIdx.x & 63;
    const int w    = blockIdx.x * 4 + (threadIdx.x >> 6);   // 0..8191
    const int n    = w & 127;
    const int slot = w >> 7;                                // 0..63
    const int sl   = seqlen[n & (BB - 1)];
    if (slot >= sl) return;

    float wreg[3][4][LL];
    {
        const float4* W4 = reinterpret_cast<const float4*>(W);
#pragma unroll
        for (int p = 0; p < 3; ++p) {
            const int base4 = p * 320 + lane * 5;   // float4 idx of lane's 20 floats
#pragma unroll
            for (int j = 0; j < 5; ++j) {
                const float4 v = W4[base4 + j];
                wreg[p][(j * 4 + 0) / 5][(j * 4 + 0) % 5] = v.x;
                wreg[p][(j * 4 + 1) / 5][(j * 4 + 1) % 5] = v.y;
                wreg[p][(j * 4 + 2) / 5][(j * 4 + 2) % 5] = v.z;
                wreg[p][(j * 4 + 3) / 5][(j * 4 + 3) % 5] = v.w;
            }
        }
    }
    float breg[LL];
#pragma unroll
    for (int l = 0; l < LL; ++l) breg[l] = bias[l];

    const float* xb = x + (size_t)n * TT * DD;
    float* lb = logits + (size_t)n * TT * LL;

#pragma unroll
    for (int pp = 0; pp < 4; ++pp) {
        const int tA = slot + 128 * pp;
        if (tA >= sl) break;                   // wave-uniform
        const int tB = tA + 64;
        const bool aB = (tB < sl);             // wave-uniform

        const float4* xpA = reinterpret_cast<const float4*>(xb + (size_t)tA * DD);
        const float4* xpB = reinterpret_cast<const float4*>(xb + (size_t)tB * DD);
        float4 vA[3], vB[3];
#pragma unroll
        for (int p = 0; p < 3; ++p) vA[p] = xpA[p * 64 + lane];
        if (aB) {
#pragma unroll
            for (int p = 0; p < 3; ++p) vB[p] = xpB[p * 64 + lane];
        }

        float accA[LL] = {0.f, 0.f, 0.f, 0.f, 0.f};
        float accB[LL] = {0.f, 0.f, 0.f, 0.f, 0.f};
#pragma unroll
        for (int p = 0; p < 3; ++p) {
#pragma unroll
            for (int l = 0; l < LL; ++l) {
                accA[l] += vA[p].x * wreg[p][0][l] + vA[p].y * wreg[p][1][l] +
                           vA[p].z * wreg[p][2][l] + vA[p].w * wreg[p][3][l];
            }
        }
        if (aB) {
#pragma unroll
            for (int p = 0; p < 3; ++p) {
#pragma unroll
                for (int l = 0; l < LL; ++l) {
                    accB[l] += vB[p].x * wreg[p][0][l] + vB[p].y * wreg[p][1][l] +
                               vB[p].z * wreg[p][2][l] + vB[p].w * wreg[p][3][l];
                }
            }
        }

        // DPP reductions (VALU pipe); 5+5 independent chains interleave.
#pragma unroll
        for (int l = 0; l < LL; ++l) accA[l] = wave_sum_dpp(accA[l]);
        if (aB) {
#pragma unroll
            for (int l = 0; l < LL; ++l) accB[l] = wave_sum_dpp(accB[l]);
        }

        if (lane == 63) {
#pragma unroll
            for (int l = 0; l < LL; ++l) lb[(size_t)tA * LL + l] = accA[l] + breg[l];
            if (aB) {
#pragma unroll
                for (int l = 0; l < LL; ++l) lb[(size_t)tB * LL + l] = accB[l] + breg[l];
            }
        }
    }
}

// ---------------------------------------------------------------------------
// Kernel B: role-split scan. UNCHANGED (measured 9.4us).
// ---------------------------------------------------------------------------
__global__ __launch_bounds__(512) void k_scan4(const float* __restrict__ logits,
                                               const int* __restrict__ label,
                                               const int* __restrict__ seqlen,
                                               const float* __restrict__ trans,
                                               float* __restrict__ out,
                                               float* __restrict__ losspart,
                                               int* __restrict__ okpart) {
    __shared__ float s_lg[2][TT * LL + 8];
    __shared__ float s_P[1600];
    __shared__ float s_Q[800];
    __shared__ float s_A[2][33 * 5];
    __shared__ float s_tr[25];
    __shared__ float s_etr[25];
    __shared__ unsigned s_mapw[2][32];
    __shared__ int s_B[2][33];
    __shared__ int s_tags[2][TT];
    __shared__ float s_ws[8];
    __shared__ int s_wok[8];

    const int tid = threadIdx.x;
    const int bid = blockIdx.x;

    if (bid < 128) {
        const int n  = bid;
        const int sl = seqlen[n & (BB - 1)];
        const float* lg = logits + (size_t)n * TT * LL;
        if (tid < 25) { const float tv = trans[tid]; s_tr[tid] = tv; s_etr[tid] = __expf(tv); }
        const int lim = sl * LL;
        for (int i = tid; i < lim; i += 512) s_lg[0][i] = lg[i];
        __syncthreads();

        {
            const bool sec = (n >= BB);
            const int* lab = label + (n & (BB - 1)) * TT;
            const int t = tid;
            float sc = 0.f;
            if (t < sl) {
                const int lv = lab[t];
                const int tg = (lv > 0) ? (sec ? lv + 1 : 1) : 0;
                sc = s_lg[0][t * 5 + tg];
                if (t >= 1) {
                    const int lp = lab[t - 1];
                    const int tp = (lp > 0) ? (sec ? lp + 1 : 1) : 0;
                    sc += s_tr[tp * 5 + tg];
                }
            }
#pragma unroll
            for (int off = 32; off > 0; off >>= 1) sc += __shfl_xor(sc, off, 64);
            if ((tid & 63) == 0) s_ws[tid >> 6] = sc;
        }

        if (tid < 320) {
            const int c = tid / 5, r = tid - 5 * c;
            float p[5];
#pragma unroll
            for (int j = 0; j < 5; ++j) p[j] = (j == r) ? 0.f : NEG_INF;
#pragma unroll
            for (int i = 0; i < 8; ++i) {
                const int t = c * 8 + 1 + i;
                const bool act = t < sl;
                const float m = fmaxf(fmaxf(fmaxf(p[0], p[1]), fmaxf(p[2], p[3])), p[4]);
                float e[5];
#pragma unroll
                for (int k = 0; k < 5; ++k) e[k] = __expf(p[k] - m);
                float nv[5];
#pragma unroll
                for (int j = 0; j < 5; ++j) {
                    float s = e[0] * s_etr[j];
#pragma unroll
                    for (int k = 1; k < 5; ++k) s += e[k] * s_etr[k * 5 + j];
                    nv[j] = m + __logf(s) + s_lg[0][t * 5 + j];
                }
#pragma unroll
                for (int j = 0; j < 5; ++j) p[j] = act ? nv[j] : p[j];
            }
#pragma unroll
            for (int j = 0; j < 5; ++j) s_P[c * 25 + r * 5 + j] = p[j];
        }
        __syncthreads();

#pragma unroll
        for (int lev = 0; lev < 6; ++lev) {
            const int np = 32 >> lev;
            const float* inb = (lev & 1) ? s_Q : s_P;
            float* outb      = (lev & 1) ? s_P : s_Q;
            for (int task = tid; task < np * 25; task += 512) {
                const int pm = task / 25;
                const int e  = task - pm * 25;
                const int r  = e / 5, j = e - 5 * r;
                const float* A  = inb + (2 * pm) * 25;
                const float* Bm = inb + (2 * pm + 1) * 25;
                float v[5];
#pragma unroll
                for (int k = 0; k < 5; ++k) v[k] = A[r * 5 + k] + Bm[k * 5 + j];
                float m = fmaxf(fmaxf(fmaxf(v[0], v[1]), fmaxf(v[2], v[3])), v[4]);
                float ssum = 0.f;
#pragma unroll
                for (int k = 0; k < 5; ++k) ssum += __expf(v[k] - m);
                outb[pm * 25 + e] = m + __logf(ssum);
            }
            __syncthreads();
        }

        if (tid == 0) {
            float b[5];
#pragma unroll
            for (int j = 0; j < 5; ++j) {
                float v[5];
#pragma unroll
                for (int k = 0; k < 5; ++k) v[k] = s_lg[0][k] + s_P[k * 5 + j];
                float m = fmaxf(fmaxf(fmaxf(v[0], v[1]), fmaxf(v[2], v[3])), v[4]);
                float ssum = 0.f;
#pragma unroll
                for (int k = 0; k < 5; ++k) ssum += __expf(v[k] - m);
                b[j] = m + __logf(ssum);
            }
            float m = fmaxf(fmaxf(fmaxf(b[0], b[1]), fmaxf(b[2], b[3])), b[4]);
            float ssum = 0.f;
#pragma unroll
            for (int j = 0; j < 5; ++j) ssum += __expf(b[j] - m);
            const float ln = m + __logf(ssum);
            float sc = 0.f;
#pragma unroll
            for (int wv = 0; wv < 8; ++wv) sc += s_ws[wv];
            losspart[n] = ln - sc;
        }
    } else {
        const int bb = bid - 128;
        const int sl = seqlen[bb];
        const float* lgA = logits + (size_t)bb * TT * LL;
        const float* lgB = logits + (size_t)(bb + BB) * TT * LL;

        if (tid < 25) s_tr[tid] = trans[tid];
        {
            const int lim = sl * LL;
            for (int i = tid; i < lim; i += 512) { s_lg[0][i] = lgA[i]; s_lg[1][i] = lgB[i]; }
        }
        __syncthreads();

        const int sid = tid / 160;
        const int rem = tid - sid * 160;
        const int cc  = rem / 5;
        const int rr  = rem - cc * 5;

        if (tid < 320) {
            float p[5];
#pragma unroll
            for (int j = 0; j < 5; ++j) p[j] = (j == rr) ? 0.f : NEG_INF;
#pragma unroll
            for (int i = 0; i < 16; ++i) {
                const int t = cc * 16 + 1 + i;
                const bool act = t < sl;
                float nv[5];
#pragma unroll
                for (int j = 0; j < 5; ++j) {
                    float b = p[0] + s_tr[j];
#pragma unroll
                    for (int k = 1; k < 5; ++k) b = fmaxf(b, p[k] + s_tr[k * 5 + j]);
                    nv[j] = b + s_lg[sid][t * 5 + j];
                }
#pragma unroll
                for (int j = 0; j < 5; ++j) p[j] = act ? nv[j] : p[j];
            }
#pragma unroll
            for (int j = 0; j < 5; ++j) s_P[sid * 800 + cc * 25 + rr * 5 + j] = p[j];
        }
        __syncthreads();

#pragma unroll
        for (int st = 1; st < 32; st <<= 1) {
            float Ar[5], Bm[25];
            const bool doit = (tid < 320) && (cc >= st);
            if (doit) {
#pragma unroll
                for (int k = 0; k < 5; ++k) Ar[k] = s_P[sid * 800 + (cc - st) * 25 + rr * 5 + k];
#pragma unroll
                for (int e = 0; e < 25; ++e) Bm[e] = s_P[sid * 800 + cc * 25 + e];
            }
            __syncthreads();
            if (doit) {
#pragma unroll
                for (int j = 0; j < 5; ++j) {
                    float b = Ar[0] + Bm[j];
#pragma unroll
                    for (int k = 1; k < 5; ++k) b = fmaxf(b, Ar[k] + Bm[k * 5 + j]);
                    s_P[sid * 800 + cc * 25 + rr * 5 + j] = b;
                }
            }
            __syncthreads();
        }

        if (tid < 320) {
            float b = s_lg[sid][0] + s_P[sid * 800 + cc * 25 + rr];
#pragma unroll
            for (int k = 1; k < 5; ++k)
                b = fmaxf(b, s_lg[sid][k] + s_P[sid * 800 + cc * 25 + k * 5 + rr]);
            s_A[sid][(cc + 1) * 5 + rr] = b;
        } else if (tid < 330) {
            const int i2 = tid - 320;
            const int s = i2 / 5, j = i2 - 5 * s;
            s_A[s][j] = s_lg[s][j];
        }
        __syncthreads();

        unsigned bpw[16];
        const int vs = tid >> 5, vc = tid & 31;
        if (tid < 64) {
            float a[5];
#pragma unroll
            for (int j = 0; j < 5; ++j) a[j] = s_A[vs][vc * 5 + j];
#pragma unroll
            for (int i = 0; i < 16; ++i) {
                const int t = vc * 16 + 1 + i;
                const bool act = t < sl;
                float nv[5]; int gi[5];
#pragma unroll
                for (int j = 0; j < 5; ++j) {
                    float b = a[0] + s_tr[j]; int g = 0;
#pragma unroll
                    for (int k = 1; k < 5; ++k) {
                        const float cn = a[k] + s_tr[k * 5 + j];
                        if (cn > b) { b = cn; g = k; }
                    }
                    nv[j] = b + s_lg[vs][t * 5 + j]; gi[j] = g;
                }
                const unsigned wv = (unsigned)gi[0] | ((unsigned)gi[1] << 3) |
                                    ((unsigned)gi[2] << 6) | ((unsigned)gi[3] << 9) |
                                    ((unsigned)gi[4] << 12);
                bpw[i] = act ? wv : IDENT_W;
#pragma unroll
                for (int j = 0; j < 5; ++j) a[j] = act ? nv[j] : a[j];
            }
            int m[5] = {0, 1, 2, 3, 4};
#pragma unroll
            for (int i = 15; i >= 0; --i) {
                const unsigned wv = bpw[i];
#pragma unroll
                for (int j = 0; j < 5; ++j) m[j] = (int)((wv >> (3 * m[j])) & 7u);
            }
            s_mapw[vs][vc] = (unsigned)m[0] | ((unsigned)m[1] << 3) | ((unsigned)m[2] << 6) |
                             ((unsigned)m[3] << 9) | ((unsigned)m[4] << 12);
        }
        __syncthreads();

        if (tid < 2) {
            const int s = tid;
            float b = s_A[s][32 * 5 + 0]; int lt = 0;
#pragma unroll
            for (int j = 1; j < 5; ++j) {
                const float cn = s_A[s][32 * 5 + j];
                if (cn > b) { b = cn; lt = j; }
            }
            unsigned wv[32];
#pragma unroll
            for (int c = 0; c < 32; ++c) wv[c] = s_mapw[s][c];
            int bc = lt; s_B[s][32] = lt;
#pragma unroll
            for (int c = 31; c >= 0; --c) { bc = (int)((wv[c] >> (3 * bc)) & 7u); s_B[s][c] = bc; }
        }
        __syncthreads();

        if (tid < 64) {
            int cur = s_B[vs][vc + 1];
#pragma unroll
            for (int i = 15; i >= 0; --i) {
                cur = (int)((bpw[i] >> (3 * cur)) & 7u);
                s_tags[vs][vc * 16 + i] = cur;
            }
        }
        __syncthreads();

        {
            const int t = tid;
            const int* lab = label + bb * TT;
            const int t1 = s_tags[0][t];
            const int t2 = s_tags[1][t];
            const int vit = (t1 == 0 || t2 == 0) ? 0 : (t2 - 1);
            out[bb * TT + t] = (float)vit;
            int ok = ((vit == lab[t]) && (t < sl)) ? 1 : 0;
#pragma unroll
            for (int off = 32; off > 0; off >>= 1) ok += __shfl_xor(ok, off, 64);
            if ((tid & 63) == 0) s_wok[tid >> 6] = ok;
        }
        __syncthreads();
        if (tid == 0) {
            int ok = 0;
#pragma unroll
            for (int wv = 0; wv < 8; ++wv) ok += s_wok[wv];
            okpart[bb] = ok;
        }
    }
}

// ---------------------------------------------------------------------------
// Kernel C: final scalars (128 threads).
// ---------------------------------------------------------------------------
__global__ __launch_bounds__(128) void k_final(const float* __restrict__ losspart,
                                               const int* __restrict__ okpart,
                                               const int* __restrict__ seqlen,
                                               float* __restrict__ out) {
    __shared__ float sf[2];
    __shared__ int s1[2], s2[2];
    const int tid = threadIdx.x;
    float f = losspart[tid];
    int ok = (tid < BB) ? okpart[tid] : 0;
    int sl = (tid < BB) ? seqlen[tid] : 0;
#pragma unroll
    for (int off = 32; off > 0; off >>= 1) {
        f  += __shfl_xor(f, off, 64);
        ok += __shfl_xor(ok, off, 64);
        sl += __shfl_xor(sl, off, 64);
    }
    if ((tid & 63) == 0) { sf[tid >> 6] = f; s1[tid >> 6] = ok; s2[tid >> 6] = sl; }
    __syncthreads();
    if (tid == 0) {
        out[BB * TT]     = (sf[0] + sf[1]) / (float)NSEQ;
        out[BB * TT + 1] = (float)(s1[0] + s1[1]) / (float)(s2[0] + s2[1]);
    }
}

// ---------------------------------------------------------------------------
extern "C" void kernel_launch(void* const* d_in, const int* in_sizes, int n_in,
                              void* d_out, int out_size, void* d_ws, size_t ws_size,
                              hipStream_t stream) {
    const float* x      = (const float*)d_in[0];
    const int*   label  = (const int*)d_in[1];
    const int*   seqlen = (const int*)d_in[2];
    const float* W      = (const float*)d_in[3];
    const float* bias   = (const float*)d_in[4];
    const float* trans  = (const float*)d_in[5];
    float* out = (float*)d_out;
    char*  ws  = (char*)d_ws;

    float* ws_logits   = (float*)(ws);                // 1,310,720 B
    float* ws_losspart = (float*)(ws + 1310720);      // 512 B
    int*   ws_okpart   = (int*)(ws + 1311232);        // 256 B

    hipLaunchKernelGGL(k_logits, dim3(2048), dim3(256), 0, stream,
                       x, W, bias, seqlen, ws_logits);
    hipLaunchKernelGGL(k_scan4, dim3(192), dim3(512), 0, stream,
                       ws_logits, label, seqlen, trans, out, ws_losspart, ws_okpart);
    hipLaunchKernelGGL(k_final, dim3(1), dim3(128), 0, stream,
                       ws_losspart, ws_okpart, seqlen, out);
}